// Round 1
// baseline (361.598 us; speedup 1.0000x reference)
//
#include <hip/hip_runtime.h>

#define CC 192          // channels
#define TOKS 36864      // 144 windows * 256 tokens
#define LOG100 4.6051701859880914f

// ---------------------------------------------------------------------------
// CPB MLP: bias_table[p][h] = sum_j relu(tab[p]·w1[j] + b1[j]) * w2[h][j]
// grid 961 blocks x 64 threads
// ---------------------------------------------------------------------------
__global__ __launch_bounds__(64) void cpb_kernel(
    const float* __restrict__ tab, const float* __restrict__ w1,
    const float* __restrict__ b1, const float* __restrict__ w2,
    float* __restrict__ bt)
{
  const int p = blockIdx.x;
  const int lane = threadIdx.x;
  const float t0 = tab[p*2+0];
  const float t1 = tab[p*2+1];
  float a0=0.f,a1=0.f,a2=0.f,a3=0.f,a4=0.f,a5=0.f;
  for (int j = lane; j < 512; j += 64) {
    float hv = fmaxf(fmaf(t0, w1[2*j], fmaf(t1, w1[2*j+1], b1[j])), 0.f);
    a0 = fmaf(hv, w2[0*512+j], a0);
    a1 = fmaf(hv, w2[1*512+j], a1);
    a2 = fmaf(hv, w2[2*512+j], a2);
    a3 = fmaf(hv, w2[3*512+j], a3);
    a4 = fmaf(hv, w2[4*512+j], a4);
    a5 = fmaf(hv, w2[5*512+j], a5);
  }
  #pragma unroll
  for (int off = 32; off > 0; off >>= 1) {
    a0 += __shfl_down(a0, off);
    a1 += __shfl_down(a1, off);
    a2 += __shfl_down(a2, off);
    a3 += __shfl_down(a3, off);
    a4 += __shfl_down(a4, off);
    a5 += __shfl_down(a5, off);
  }
  if (lane == 0) {
    bt[p*6+0]=a0; bt[p*6+1]=a1; bt[p*6+2]=a2;
    bt[p*6+3]=a3; bt[p*6+4]=a4; bt[p*6+5]=a5;
  }
}

// ---------------------------------------------------------------------------
// Expand to TRANSPOSED rpb: rpbT[h][m][n] = 16*sigmoid(bt[idx[n][m]][h])
// grid 1536 x 256
// ---------------------------------------------------------------------------
__global__ __launch_bounds__(256) void rpb_kernel(
    const float* __restrict__ bt, const int* __restrict__ idx,
    float* __restrict__ rpbT)
{
  const int g = blockIdx.x * 256 + threadIdx.x;   // h*65536 + m*256 + n
  const int n = g & 255;
  const int m = (g >> 8) & 255;
  const int h = g >> 16;
  const float v = bt[idx[n*256 + m]*6 + h];
  rpbT[g] = 16.f / (1.f + __expf(-v));
}

// ---------------------------------------------------------------------------
// QKV: gather(shift+window) GEMM (36864 x 576 x 192) + bias + cosine norm
// grid (576, 9) x 256.  BM=BN=BK=64, 4x4 microtile.
// Outputs q/k/v in (win*6+h, n, d) layout; q pre-scaled by exp(min(ls,log100)).
// ---------------------------------------------------------------------------
__global__ __launch_bounds__(256) void qkv_kernel(
    const float* __restrict__ x, const float* __restrict__ w,
    const float* __restrict__ q_bias, const float* __restrict__ v_bias,
    const float* __restrict__ ls,
    float* __restrict__ qb, float* __restrict__ kb, float* __restrict__ vb)
{
  __shared__ float As[64][64];   // [k][m]
  __shared__ float Bs[64][64];   // [k][n]
  const int tid = threadIdx.x;
  const int row0 = blockIdx.x * 64;
  const int f0 = blockIdx.y * 64;
  const int lrow = tid & 63;
  const int chunk = tid >> 6;     // 0..3

  // gather address for token row0+lrow
  const int gt = row0 + lrow;
  const int wb = gt >> 8;
  const int n  = gt & 255;
  const int b  = wb / 36;
  const int wq = wb - b*36;
  const int wy = wq / 6;
  const int wx = wq - wy*6;
  const int iy = (wy*16 + (n >> 4) + 8) % 96;
  const int ix = (wx*16 + (n & 15) + 8) % 96;
  const float* arow = x + ((b*96 + iy)*96 + ix)*CC + chunk*16;
  const float* brow = w + (f0 + lrow)*CC + chunk*16;

  const int ty = tid >> 4;
  const int tx = tid & 15;
  float acc[4][4] = {};

  for (int kc = 0; kc < CC; kc += 64) {
    #pragma unroll
    for (int u = 0; u < 4; u++) {
      const float4 av = *(const float4*)(arow + kc + u*4);
      As[chunk*16 + u*4 + 0][lrow] = av.x;
      As[chunk*16 + u*4 + 1][lrow] = av.y;
      As[chunk*16 + u*4 + 2][lrow] = av.z;
      As[chunk*16 + u*4 + 3][lrow] = av.w;
      const float4 bv = *(const float4*)(brow + kc + u*4);
      Bs[chunk*16 + u*4 + 0][lrow] = bv.x;
      Bs[chunk*16 + u*4 + 1][lrow] = bv.y;
      Bs[chunk*16 + u*4 + 2][lrow] = bv.z;
      Bs[chunk*16 + u*4 + 3][lrow] = bv.w;
    }
    __syncthreads();
    #pragma unroll 16
    for (int k = 0; k < 64; k++) {
      const float4 av = *(const float4*)&As[k][ty*4];
      const float4 bv = *(const float4*)&Bs[k][tx*4];
      acc[0][0] = fmaf(av.x, bv.x, acc[0][0]);
      acc[0][1] = fmaf(av.x, bv.y, acc[0][1]);
      acc[0][2] = fmaf(av.x, bv.z, acc[0][2]);
      acc[0][3] = fmaf(av.x, bv.w, acc[0][3]);
      acc[1][0] = fmaf(av.y, bv.x, acc[1][0]);
      acc[1][1] = fmaf(av.y, bv.y, acc[1][1]);
      acc[1][2] = fmaf(av.y, bv.z, acc[1][2]);
      acc[1][3] = fmaf(av.y, bv.w, acc[1][3]);
      acc[2][0] = fmaf(av.z, bv.x, acc[2][0]);
      acc[2][1] = fmaf(av.z, bv.y, acc[2][1]);
      acc[2][2] = fmaf(av.z, bv.z, acc[2][2]);
      acc[2][3] = fmaf(av.z, bv.w, acc[2][3]);
      acc[3][0] = fmaf(av.w, bv.x, acc[3][0]);
      acc[3][1] = fmaf(av.w, bv.y, acc[3][1]);
      acc[3][2] = fmaf(av.w, bv.z, acc[3][2]);
      acc[3][3] = fmaf(av.w, bv.w, acc[3][3]);
    }
    __syncthreads();
  }

  const int part  = f0 / CC;            // 0=q 1=k 2=v (uniform per block)
  const int fcol  = f0 - part*CC;       // 0,64,128
  const int h     = (fcol + tx*4) >> 5;
  const int dbase = (fcol + tx*4) & 31;
  float* dst;
  if (part == 0) {
    const float scale = __expf(fminf(ls[h], LOG100));
    #pragma unroll
    for (int i = 0; i < 4; i++) {
      #pragma unroll
      for (int j = 0; j < 4; j++) acc[i][j] += q_bias[h*32 + dbase + j];
      float ss = acc[i][0]*acc[i][0] + acc[i][1]*acc[i][1]
               + acc[i][2]*acc[i][2] + acc[i][3]*acc[i][3];
      ss += __shfl_xor(ss, 1);
      ss += __shfl_xor(ss, 2);
      ss += __shfl_xor(ss, 4);
      const float rn = scale / (sqrtf(ss) + 1e-12f);
      #pragma unroll
      for (int j = 0; j < 4; j++) acc[i][j] *= rn;
    }
    dst = qb;
  } else if (part == 1) {
    #pragma unroll
    for (int i = 0; i < 4; i++) {
      float ss = acc[i][0]*acc[i][0] + acc[i][1]*acc[i][1]
               + acc[i][2]*acc[i][2] + acc[i][3]*acc[i][3];
      ss += __shfl_xor(ss, 1);
      ss += __shfl_xor(ss, 2);
      ss += __shfl_xor(ss, 4);
      const float rn = 1.f / (sqrtf(ss) + 1e-12f);
      #pragma unroll
      for (int j = 0; j < 4; j++) acc[i][j] *= rn;
    }
    dst = kb;
  } else {
    #pragma unroll
    for (int i = 0; i < 4; i++)
      #pragma unroll
      for (int j = 0; j < 4; j++) acc[i][j] += v_bias[h*32 + dbase + j];
    dst = vb;
  }
  #pragma unroll
  for (int i = 0; i < 4; i++) {
    const int g2  = row0 + ty*4 + i;
    const int wb2 = g2 >> 8;
    const int n2  = g2 & 255;
    const float4 val = make_float4(acc[i][0], acc[i][1], acc[i][2], acc[i][3]);
    *(float4*)(dst + (((wb2*6 + h)*256 + n2) << 5) + dbase) = val;
  }
}

// ---------------------------------------------------------------------------
// Attention: one block per (window, head); thread = query row.
// Fixed softmax bound (scale+16) -> no online-max tracking.
// grid 864 x 256
// ---------------------------------------------------------------------------
__global__ __launch_bounds__(256) void attn_kernel(
    const float* __restrict__ qb, const float* __restrict__ kb,
    const float* __restrict__ vb, const float* __restrict__ rpbT,
    const float* __restrict__ mask, const float* __restrict__ ls,
    float* __restrict__ aout)
{
  __shared__ float kshm[256*32];
  __shared__ float vshm[256*32];
  const int tid = threadIdx.x;
  const int bx = blockIdx.x;          // wb*6 + h
  const int wb = bx / 6;
  const int h  = bx - wb*6;
  const size_t slice = (size_t)bx * (256*32);

  const float4* kg = (const float4*)(kb + slice);
  const float4* vg = (const float4*)(vb + slice);
  float4* ks4 = (float4*)kshm;
  float4* vs4 = (float4*)vshm;
  #pragma unroll
  for (int i = 0; i < 8; i++) {
    ks4[tid + i*256] = kg[tid + i*256];
    vs4[tid + i*256] = vg[tid + i*256];
  }
  float q[32];
  {
    const float4* qg = (const float4*)(qb + slice + tid*32);
    #pragma unroll
    for (int i = 0; i < 8; i++) {
      const float4 t = qg[i];
      q[i*4+0]=t.x; q[i*4+1]=t.y; q[i*4+2]=t.z; q[i*4+3]=t.w;
    }
  }
  const float bound = __expf(fminf(ls[h], LOG100)) + 16.0f;
  __syncthreads();

  const float* rp = rpbT + h*65536 + tid;          // rpbT[h][m][row]
  const float* mp = mask + (wb % 36)*65536 + tid;  // mask symmetric -> [m][row]
  float o[32] = {};
  float denom = 0.f;
  for (int m = 0; m < 256; m++) {
    const float* kr = kshm + m*32;
    float s0=0.f,s1=0.f,s2=0.f,s3=0.f;
    #pragma unroll
    for (int d = 0; d < 32; d += 4) {
      s0 = fmaf(q[d+0], kr[d+0], s0);
      s1 = fmaf(q[d+1], kr[d+1], s1);
      s2 = fmaf(q[d+2], kr[d+2], s2);
      s3 = fmaf(q[d+3], kr[d+3], s3);
    }
    const float s = (s0+s1)+(s2+s3) + rp[m*256] + mp[m*256];
    const float p = __expf(s - bound);
    denom += p;
    const float* vr = vshm + m*32;
    #pragma unroll
    for (int d = 0; d < 32; d++) o[d] = fmaf(p, vr[d], o[d]);
  }
  const float inv = 1.f / denom;
  float4* op = (float4*)(aout + (size_t)(wb*256 + tid)*CC + h*32);
  #pragma unroll
  for (int i = 0; i < 8; i++)
    op[i] = make_float4(o[i*4+0]*inv, o[i*4+1]*inv, o[i*4+2]*inv, o[i*4+3]*inv);
}

// ---------------------------------------------------------------------------
// Proj: (36864 x 192 x 192) GEMM + bias, scatter through reverse shift.
// grid (576, 3) x 256
// ---------------------------------------------------------------------------
__global__ __launch_bounds__(256) void proj_kernel(
    const float* __restrict__ ain, const float* __restrict__ w,
    const float* __restrict__ pb, float* __restrict__ out)
{
  __shared__ float As[64][64];
  __shared__ float Bs[64][64];
  const int tid = threadIdx.x;
  const int row0 = blockIdx.x * 64;
  const int n0 = blockIdx.y * 64;
  const int lrow = tid & 63;
  const int chunk = tid >> 6;
  const float* arow = ain + (size_t)(row0 + lrow)*CC + chunk*16;
  const float* brow = w + (size_t)(n0 + lrow)*CC + chunk*16;
  const int ty = tid >> 4;
  const int tx = tid & 15;
  float acc[4][4] = {};

  for (int kc = 0; kc < CC; kc += 64) {
    #pragma unroll
    for (int u = 0; u < 4; u++) {
      const float4 av = *(const float4*)(arow + kc + u*4);
      As[chunk*16 + u*4 + 0][lrow] = av.x;
      As[chunk*16 + u*4 + 1][lrow] = av.y;
      As[chunk*16 + u*4 + 2][lrow] = av.z;
      As[chunk*16 + u*4 + 3][lrow] = av.w;
      const float4 bv = *(const float4*)(brow + kc + u*4);
      Bs[chunk*16 + u*4 + 0][lrow] = bv.x;
      Bs[chunk*16 + u*4 + 1][lrow] = bv.y;
      Bs[chunk*16 + u*4 + 2][lrow] = bv.z;
      Bs[chunk*16 + u*4 + 3][lrow] = bv.w;
    }
    __syncthreads();
    #pragma unroll 16
    for (int k = 0; k < 64; k++) {
      const float4 av = *(const float4*)&As[k][ty*4];
      const float4 bv = *(const float4*)&Bs[k][tx*4];
      acc[0][0] = fmaf(av.x, bv.x, acc[0][0]);
      acc[0][1] = fmaf(av.x, bv.y, acc[0][1]);
      acc[0][2] = fmaf(av.x, bv.z, acc[0][2]);
      acc[0][3] = fmaf(av.x, bv.w, acc[0][3]);
      acc[1][0] = fmaf(av.y, bv.x, acc[1][0]);
      acc[1][1] = fmaf(av.y, bv.y, acc[1][1]);
      acc[1][2] = fmaf(av.y, bv.z, acc[1][2]);
      acc[1][3] = fmaf(av.y, bv.w, acc[1][3]);
      acc[2][0] = fmaf(av.z, bv.x, acc[2][0]);
      acc[2][1] = fmaf(av.z, bv.y, acc[2][1]);
      acc[2][2] = fmaf(av.z, bv.z, acc[2][2]);
      acc[2][3] = fmaf(av.z, bv.w, acc[2][3]);
      acc[3][0] = fmaf(av.w, bv.x, acc[3][0]);
      acc[3][1] = fmaf(av.w, bv.y, acc[3][1]);
      acc[3][2] = fmaf(av.w, bv.z, acc[3][2]);
      acc[3][3] = fmaf(av.w, bv.w, acc[3][3]);
    }
    __syncthreads();
  }

  const int col = n0 + tx*4;
  const float4 bias = *(const float4*)(pb + col);
  #pragma unroll
  for (int i = 0; i < 4; i++) {
    const int g2  = row0 + ty*4 + i;
    const int wb2 = g2 >> 8;
    const int n2  = g2 & 255;
    const int b   = wb2 / 36;
    const int wq  = wb2 - b*36;
    const int wy  = wq / 6;
    const int wx  = wq - wy*6;
    const int iy  = (wy*16 + (n2 >> 4) + 8) % 96;
    const int ix  = (wx*16 + (n2 & 15) + 8) % 96;
    const float4 v = make_float4(acc[i][0]+bias.x, acc[i][1]+bias.y,
                                 acc[i][2]+bias.z, acc[i][3]+bias.w);
    *(float4*)(out + ((b*96 + iy)*96 + ix)*CC + col) = v;
  }
}

extern "C" void kernel_launch(void* const* d_in, const int* in_sizes, int n_in,
                              void* d_out, int out_size, void* d_ws, size_t ws_size,
                              hipStream_t stream) {
  const float* x      = (const float*)d_in[0];
  const float* qkv_w  = (const float*)d_in[1];
  const float* q_bias = (const float*)d_in[2];
  const float* v_bias = (const float*)d_in[3];
  const float* ls     = (const float*)d_in[4];
  const float* cpb_w1 = (const float*)d_in[5];
  const float* cpb_b1 = (const float*)d_in[6];
  const float* cpb_w2 = (const float*)d_in[7];
  const float* proj_w = (const float*)d_in[8];
  const float* proj_b = (const float*)d_in[9];
  const float* tab    = (const float*)d_in[10];
  const int*   idx    = (const int*)d_in[11];
  const float* mask   = (const float*)d_in[12];
  float* out = (float*)d_out;

  float* qb   = (float*)d_ws;
  float* kb   = qb + 7077888;
  float* vb   = kb + 7077888;
  float* aout = vb + 7077888;
  float* rpbT = aout + 7077888;
  float* bt   = rpbT + 393216;

  cpb_kernel<<<961, 64, 0, stream>>>(tab, cpb_w1, cpb_b1, cpb_w2, bt);
  rpb_kernel<<<1536, 256, 0, stream>>>(bt, idx, rpbT);
  qkv_kernel<<<dim3(576, 9), 256, 0, stream>>>(x, qkv_w, q_bias, v_bias, ls,
                                               qb, kb, vb);
  attn_kernel<<<864, 256, 0, stream>>>(qb, kb, vb, rpbT, mask, ls, aout);
  proj_kernel<<<dim3(576, 3), 256, 0, stream>>>(aout, proj_w, proj_b, out);
}

// Round 2
// 231.176 us; speedup vs baseline: 1.5642x; 1.5642x over previous
//
#include <hip/hip_runtime.h>

#define CC 192
#define LOG100 4.6051701859880914f

typedef __attribute__((ext_vector_type(8))) short short8v;
typedef __attribute__((ext_vector_type(4))) short short4v;
typedef __attribute__((ext_vector_type(4))) float f32x4;

static __device__ __forceinline__ ushort f2bf(float f) {
  union { float f; unsigned u; } v; v.f = f;
  unsigned r = v.u + 0x7FFF + ((v.u >> 16) & 1);
  return (ushort)(r >> 16);
}

static __device__ __forceinline__ f32x4 mfma16(short4v a, short4v b, f32x4 c) {
#if __has_builtin(__builtin_amdgcn_mfma_f32_16x16x16bf16_1k)
  return __builtin_amdgcn_mfma_f32_16x16x16bf16_1k(a, b, c, 0, 0, 0);
#else
  asm("v_mfma_f32_16x16x16_bf16 %0, %1, %2, %0" : "+v"(c) : "v"(a), "v"(b));
  return c;
#endif
}

// ---------------------------------------------------------------------------
// CPB MLP: bias_table[p][h]
// ---------------------------------------------------------------------------
__global__ __launch_bounds__(64) void cpb_kernel(
    const float* __restrict__ tab, const float* __restrict__ w1,
    const float* __restrict__ b1, const float* __restrict__ w2,
    float* __restrict__ bt)
{
  const int p = blockIdx.x;
  const int lane = threadIdx.x;
  const float t0 = tab[p*2+0];
  const float t1 = tab[p*2+1];
  float a0=0.f,a1=0.f,a2=0.f,a3=0.f,a4=0.f,a5=0.f;
  for (int j = lane; j < 512; j += 64) {
    float hv = fmaxf(fmaf(t0, w1[2*j], fmaf(t1, w1[2*j+1], b1[j])), 0.f);
    a0 = fmaf(hv, w2[0*512+j], a0);
    a1 = fmaf(hv, w2[1*512+j], a1);
    a2 = fmaf(hv, w2[2*512+j], a2);
    a3 = fmaf(hv, w2[3*512+j], a3);
    a4 = fmaf(hv, w2[4*512+j], a4);
    a5 = fmaf(hv, w2[5*512+j], a5);
  }
  #pragma unroll
  for (int off = 32; off > 0; off >>= 1) {
    a0 += __shfl_down(a0, off);
    a1 += __shfl_down(a1, off);
    a2 += __shfl_down(a2, off);
    a3 += __shfl_down(a3, off);
    a4 += __shfl_down(a4, off);
    a5 += __shfl_down(a5, off);
  }
  if (lane == 0) {
    bt[p*6+0]=a0; bt[p*6+1]=a1; bt[p*6+2]=a2;
    bt[p*6+3]=a3; bt[p*6+4]=a4; bt[p*6+5]=a5;
  }
}

// ---------------------------------------------------------------------------
// rpb in [h][n][m] orientation: rpb2[h][n][m] = 16*sigmoid(bt[idx[n][m]][h])
// ---------------------------------------------------------------------------
__global__ __launch_bounds__(256) void rpb_kernel(
    const float* __restrict__ bt, const int* __restrict__ idx,
    float* __restrict__ rpb2)
{
  const int gidx = blockIdx.x * 256 + threadIdx.x;  // h*65536 + n*256 + m
  const int nm = gidx & 65535;                      // n*256+m
  const int h = gidx >> 16;
  const float v = bt[idx[nm]*6 + h];
  rpb2[gidx] = 16.f / (1.f + __expf(-v));
}

// ---------------------------------------------------------------------------
// QKV: gather GEMM + bias + cosine norm. V written TRANSPOSED ([d][n] per
// (win,head) slice) via LDS transpose so attn can stage V-frags contiguously.
// ---------------------------------------------------------------------------
__global__ __launch_bounds__(256) void qkv_kernel(
    const float* __restrict__ x, const float* __restrict__ w,
    const float* __restrict__ q_bias, const float* __restrict__ v_bias,
    const float* __restrict__ ls,
    float* __restrict__ qb, float* __restrict__ kb, float* __restrict__ vbT)
{
  __shared__ float sh[2][64][64];
  #define As (sh[0])
  #define Bs (sh[1])
  const int tid = threadIdx.x;
  const int row0 = blockIdx.x * 64;
  const int f0 = blockIdx.y * 64;
  const int lrow = tid & 63;
  const int chunk = tid >> 6;

  const int gt = row0 + lrow;
  const int wb = gt >> 8;
  const int n  = gt & 255;
  const int b  = wb / 36;
  const int wq = wb - b*36;
  const int wy = wq / 6;
  const int wx = wq - wy*6;
  const int iy = (wy*16 + (n >> 4) + 8) % 96;
  const int ix = (wx*16 + (n & 15) + 8) % 96;
  const float* arow = x + ((b*96 + iy)*96 + ix)*CC + chunk*16;
  const float* brow = w + (f0 + lrow)*CC + chunk*16;

  const int ty = tid >> 4;
  const int tx = tid & 15;
  float acc[4][4] = {};

  for (int kc = 0; kc < CC; kc += 64) {
    #pragma unroll
    for (int u = 0; u < 4; u++) {
      const float4 av = *(const float4*)(arow + kc + u*4);
      As[chunk*16 + u*4 + 0][lrow] = av.x;
      As[chunk*16 + u*4 + 1][lrow] = av.y;
      As[chunk*16 + u*4 + 2][lrow] = av.z;
      As[chunk*16 + u*4 + 3][lrow] = av.w;
      const float4 bv = *(const float4*)(brow + kc + u*4);
      Bs[chunk*16 + u*4 + 0][lrow] = bv.x;
      Bs[chunk*16 + u*4 + 1][lrow] = bv.y;
      Bs[chunk*16 + u*4 + 2][lrow] = bv.z;
      Bs[chunk*16 + u*4 + 3][lrow] = bv.w;
    }
    __syncthreads();
    #pragma unroll 16
    for (int k = 0; k < 64; k++) {
      const float4 av = *(const float4*)&As[k][ty*4];
      const float4 bv = *(const float4*)&Bs[k][tx*4];
      acc[0][0] = fmaf(av.x, bv.x, acc[0][0]);
      acc[0][1] = fmaf(av.x, bv.y, acc[0][1]);
      acc[0][2] = fmaf(av.x, bv.z, acc[0][2]);
      acc[0][3] = fmaf(av.x, bv.w, acc[0][3]);
      acc[1][0] = fmaf(av.y, bv.x, acc[1][0]);
      acc[1][1] = fmaf(av.y, bv.y, acc[1][1]);
      acc[1][2] = fmaf(av.y, bv.z, acc[1][2]);
      acc[1][3] = fmaf(av.y, bv.w, acc[1][3]);
      acc[2][0] = fmaf(av.z, bv.x, acc[2][0]);
      acc[2][1] = fmaf(av.z, bv.y, acc[2][1]);
      acc[2][2] = fmaf(av.z, bv.z, acc[2][2]);
      acc[2][3] = fmaf(av.z, bv.w, acc[2][3]);
      acc[3][0] = fmaf(av.w, bv.x, acc[3][0]);
      acc[3][1] = fmaf(av.w, bv.y, acc[3][1]);
      acc[3][2] = fmaf(av.w, bv.z, acc[3][2]);
      acc[3][3] = fmaf(av.w, bv.w, acc[3][3]);
    }
    __syncthreads();
  }

  const int part  = f0 / CC;
  const int fcol  = f0 - part*CC;
  const int h     = (fcol + tx*4) >> 5;
  const int dbase = (fcol + tx*4) & 31;

  if (part == 0) {
    const float scale = __expf(fminf(ls[h], LOG100));
    #pragma unroll
    for (int i = 0; i < 4; i++) {
      #pragma unroll
      for (int j = 0; j < 4; j++) acc[i][j] += q_bias[h*32 + dbase + j];
      float ss = acc[i][0]*acc[i][0] + acc[i][1]*acc[i][1]
               + acc[i][2]*acc[i][2] + acc[i][3]*acc[i][3];
      ss += __shfl_xor(ss, 1);
      ss += __shfl_xor(ss, 2);
      ss += __shfl_xor(ss, 4);
      const float rn = scale / (sqrtf(ss) + 1e-12f);
      #pragma unroll
      for (int j = 0; j < 4; j++) acc[i][j] *= rn;
    }
    #pragma unroll
    for (int i = 0; i < 4; i++) {
      const int g2  = row0 + ty*4 + i;
      *(float4*)(qb + ((((g2>>8)*6 + h)*256 + (g2&255)) << 5) + dbase) =
          make_float4(acc[i][0], acc[i][1], acc[i][2], acc[i][3]);
    }
  } else if (part == 1) {
    #pragma unroll
    for (int i = 0; i < 4; i++) {
      float ss = acc[i][0]*acc[i][0] + acc[i][1]*acc[i][1]
               + acc[i][2]*acc[i][2] + acc[i][3]*acc[i][3];
      ss += __shfl_xor(ss, 1);
      ss += __shfl_xor(ss, 2);
      ss += __shfl_xor(ss, 4);
      const float rn = 1.f / (sqrtf(ss) + 1e-12f);
      #pragma unroll
      for (int j = 0; j < 4; j++) acc[i][j] *= rn;
    }
    #pragma unroll
    for (int i = 0; i < 4; i++) {
      const int g2  = row0 + ty*4 + i;
      *(float4*)(kb + ((((g2>>8)*6 + h)*256 + (g2&255)) << 5) + dbase) =
          make_float4(acc[i][0], acc[i][1], acc[i][2], acc[i][3]);
    }
  } else {
    // V: add bias, transpose 64x64 tile through LDS, store [d][n] layout.
    #pragma unroll
    for (int i = 0; i < 4; i++)
      #pragma unroll
      for (int j = 0; j < 4; j++) acc[i][j] += v_bias[h*32 + dbase + j];
    float* scr = &sh[0][0][0];        // >= 64*65 floats
    __syncthreads();
    #pragma unroll
    for (int i = 0; i < 4; i++)
      #pragma unroll
      for (int j = 0; j < 4; j++)
        scr[(tx*4+j)*65 + (ty*4+i)] = acc[i][j];
    __syncthreads();
    const int dp = tid >> 2;          // 0..63 (dim within 64-col slab)
    const int qq = tid & 3;
    const int d  = fcol + dp;
    const int hh = d >> 5;
    const int dd = d & 31;
    const int wb2   = row0 >> 8;
    const int nbase = row0 & 255;
    float* dst = vbT + ((size_t)(wb2*6 + hh)*32 + dd)*256 + nbase + qq*16;
    #pragma unroll
    for (int u = 0; u < 4; u++) {
      *(float4*)(dst + u*4) = make_float4(scr[dp*65 + qq*16 + u*4 + 0],
                                          scr[dp*65 + qq*16 + u*4 + 1],
                                          scr[dp*65 + qq*16 + u*4 + 2],
                                          scr[dp*65 + qq*16 + u*4 + 3]);
    }
  }
  #undef As
  #undef Bs
}

// ---------------------------------------------------------------------------
// MFMA attention. Block = (window, head), 4 waves. S^T = mfma(K,Q) so the
// C/D layout (row=key) matches the PV 16x16x16 B-frag k-layout -> zero-shuffle
// P. Fixed softmax bound; mask computed arithmetically; rpb [h][n][m] float4.
// ---------------------------------------------------------------------------
__global__ __launch_bounds__(256) void attn_kernel(
    const float* __restrict__ qb, const float* __restrict__ kb,
    const float* __restrict__ vbT, const float* __restrict__ rpb2,
    const float* __restrict__ ls, float* __restrict__ aout)
{
  __shared__ short8v kf[16][64];      // [key-tile][lane] A-frags of K
  __shared__ short4v vf[16][2][64];   // [m-chunk][d-tile][lane] A-frags of V^T
  const int tid = threadIdx.x;
  const int bx = blockIdx.x;          // wb*6 + h
  const int wb = bx / 6;
  const int h  = bx - wb*6;
  const size_t slice = (size_t)bx * 8192;

  // ---- stage K fragments: thread t covers token t, all 4 k-octets ----
  {
    const int j = tid >> 4, r = tid & 15;
    const float* src = kb + slice + (size_t)tid * 32;
    #pragma unroll
    for (int g4 = 0; g4 < 4; g4++) {
      const float4 a = *(const float4*)(src + g4*8);
      const float4 b2 = *(const float4*)(src + g4*8 + 4);
      short8v kv;
      kv[0]=f2bf(a.x); kv[1]=f2bf(a.y); kv[2]=f2bf(a.z); kv[3]=f2bf(a.w);
      kv[4]=f2bf(b2.x); kv[5]=f2bf(b2.y); kv[6]=f2bf(b2.z); kv[7]=f2bf(b2.w);
      kf[j][16*g4 + r] = kv;
    }
  }
  // ---- stage V fragments from transposed V ----
  {
    const int mc = tid >> 4, r = tid & 15;
    #pragma unroll
    for (int dt = 0; dt < 2; dt++) {
      const float* src = vbT + slice + (size_t)(dt*16 + r)*256 + mc*16;
      #pragma unroll
      for (int g4 = 0; g4 < 4; g4++) {
        const float4 a = *(const float4*)(src + g4*4);
        short4v vv;
        vv[0]=f2bf(a.x); vv[1]=f2bf(a.y); vv[2]=f2bf(a.z); vv[3]=f2bf(a.w);
        vf[mc][dt][16*g4 + r] = vv;
      }
    }
  }
  const float bound = __expf(fminf(ls[h], LOG100)) + 16.0f;
  __syncthreads();

  const int lane = tid & 63;
  const int wv   = tid >> 6;
  const int g    = lane >> 4;      // quarter (k-octet / key sub-row)
  const int c    = lane & 15;      // query column within tile

  const int wq = wb % 36;
  const int wy = wq / 6;
  const int wx = wq - wy*6;
  const bool lastY = (wy == 5);
  const float xmask = ((wx == 5) && ((g >= 2) != (c >= 8))) ? -100.f : 0.f;

  #pragma unroll
  for (int ii = 0; ii < 4; ii++) {
    const int i = wv*4 + ii;                 // query row-tile
    const bool iHi = (i >= 8);
    // Q fragment direct from global
    short8v bq;
    {
      const float* qrow = qb + slice + (size_t)(i*16 + c)*32 + 8*g;
      const float4 a = *(const float4*)qrow;
      const float4 b2 = *(const float4*)(qrow + 4);
      bq[0]=f2bf(a.x); bq[1]=f2bf(a.y); bq[2]=f2bf(a.z); bq[3]=f2bf(a.w);
      bq[4]=f2bf(b2.x); bq[5]=f2bf(b2.y); bq[6]=f2bf(b2.z); bq[7]=f2bf(b2.w);
    }
    const float* rp = rpb2 + h*65536 + (i*16 + c)*256 + 4*g;
    f32x4 o0 = {0.f,0.f,0.f,0.f};
    f32x4 o1 = {0.f,0.f,0.f,0.f};
    float dsum = 0.f;
    #pragma unroll
    for (int j = 0; j < 16; j++) {
      f32x4 zero = {0.f,0.f,0.f,0.f};
      f32x4 s = __builtin_amdgcn_mfma_f32_16x16x32_bf16(kf[j][lane], bq, zero, 0, 0, 0);
      const float4 b4 = *(const float4*)(rp + j*16);
      const float madd = (lastY && ((j >= 8) != iHi)) ? -100.f : xmask;
      const float adj = madd - bound;
      const float p0 = __expf(s[0] + b4.x + adj);
      const float p1 = __expf(s[1] + b4.y + adj);
      const float p2 = __expf(s[2] + b4.z + adj);
      const float p3 = __expf(s[3] + b4.w + adj);
      dsum += (p0 + p1) + (p2 + p3);
      short4v pf;
      pf[0]=f2bf(p0); pf[1]=f2bf(p1); pf[2]=f2bf(p2); pf[3]=f2bf(p3);
      o0 = mfma16(vf[j][0][lane], pf, o0);
      o1 = mfma16(vf[j][1][lane], pf, o1);
    }
    float d = dsum + __shfl_xor(dsum, 16);
    d += __shfl_xor(d, 32);
    const float inv = 1.f / d;
    float* obase = aout + (size_t)(wb*256 + i*16 + c)*CC + h*32 + 4*g;
    *(float4*)obase      = make_float4(o0[0]*inv, o0[1]*inv, o0[2]*inv, o0[3]*inv);
    *(float4*)(obase+16) = make_float4(o1[0]*inv, o1[1]*inv, o1[2]*inv, o1[3]*inv);
  }
}

// ---------------------------------------------------------------------------
// Proj GEMM + bias + reverse-shift scatter
// ---------------------------------------------------------------------------
__global__ __launch_bounds__(256) void proj_kernel(
    const float* __restrict__ ain, const float* __restrict__ w,
    const float* __restrict__ pb, float* __restrict__ out)
{
  __shared__ float As[64][64];
  __shared__ float Bs[64][64];
  const int tid = threadIdx.x;
  const int row0 = blockIdx.x * 64;
  const int n0 = blockIdx.y * 64;
  const int lrow = tid & 63;
  const int chunk = tid >> 6;
  const float* arow = ain + (size_t)(row0 + lrow)*CC + chunk*16;
  const float* brow = w + (size_t)(n0 + lrow)*CC + chunk*16;
  const int ty = tid >> 4;
  const int tx = tid & 15;
  float acc[4][4] = {};

  for (int kc = 0; kc < CC; kc += 64) {
    #pragma unroll
    for (int u = 0; u < 4; u++) {
      const float4 av = *(const float4*)(arow + kc + u*4);
      As[chunk*16 + u*4 + 0][lrow] = av.x;
      As[chunk*16 + u*4 + 1][lrow] = av.y;
      As[chunk*16 + u*4 + 2][lrow] = av.z;
      As[chunk*16 + u*4 + 3][lrow] = av.w;
      const float4 bv = *(const float4*)(brow + kc + u*4);
      Bs[chunk*16 + u*4 + 0][lrow] = bv.x;
      Bs[chunk*16 + u*4 + 1][lrow] = bv.y;
      Bs[chunk*16 + u*4 + 2][lrow] = bv.z;
      Bs[chunk*16 + u*4 + 3][lrow] = bv.w;
    }
    __syncthreads();
    #pragma unroll 16
    for (int k = 0; k < 64; k++) {
      const float4 av = *(const float4*)&As[k][ty*4];
      const float4 bv = *(const float4*)&Bs[k][tx*4];
      acc[0][0] = fmaf(av.x, bv.x, acc[0][0]);
      acc[0][1] = fmaf(av.x, bv.y, acc[0][1]);
      acc[0][2] = fmaf(av.x, bv.z, acc[0][2]);
      acc[0][3] = fmaf(av.x, bv.w, acc[0][3]);
      acc[1][0] = fmaf(av.y, bv.x, acc[1][0]);
      acc[1][1] = fmaf(av.y, bv.y, acc[1][1]);
      acc[1][2] = fmaf(av.y, bv.z, acc[1][2]);
      acc[1][3] = fmaf(av.y, bv.w, acc[1][3]);
      acc[2][0] = fmaf(av.z, bv.x, acc[2][0]);
      acc[2][1] = fmaf(av.z, bv.y, acc[2][1]);
      acc[2][2] = fmaf(av.z, bv.z, acc[2][2]);
      acc[2][3] = fmaf(av.z, bv.w, acc[2][3]);
      acc[3][0] = fmaf(av.w, bv.x, acc[3][0]);
      acc[3][1] = fmaf(av.w, bv.y, acc[3][1]);
      acc[3][2] = fmaf(av.w, bv.z, acc[3][2]);
      acc[3][3] = fmaf(av.w, bv.w, acc[3][3]);
    }
    __syncthreads();
  }

  const int col = n0 + tx*4;
  const float4 bias = *(const float4*)(pb + col);
  #pragma unroll
  for (int i = 0; i < 4; i++) {
    const int g2  = row0 + ty*4 + i;
    const int wb2 = g2 >> 8;
    const int n2  = g2 & 255;
    const int b   = wb2 / 36;
    const int wq  = wb2 - b*36;
    const int wy  = wq / 6;
    const int wx  = wq - wy*6;
    const int iy  = (wy*16 + (n2 >> 4) + 8) % 96;
    const int ix  = (wx*16 + (n2 & 15) + 8) % 96;
    *(float4*)(out + ((b*96 + iy)*96 + ix)*CC + col) =
        make_float4(acc[i][0]+bias.x, acc[i][1]+bias.y,
                    acc[i][2]+bias.z, acc[i][3]+bias.w);
  }
}

extern "C" void kernel_launch(void* const* d_in, const int* in_sizes, int n_in,
                              void* d_out, int out_size, void* d_ws, size_t ws_size,
                              hipStream_t stream) {
  const float* x      = (const float*)d_in[0];
  const float* qkv_w  = (const float*)d_in[1];
  const float* q_bias = (const float*)d_in[2];
  const float* v_bias = (const float*)d_in[3];
  const float* ls     = (const float*)d_in[4];
  const float* cpb_w1 = (const float*)d_in[5];
  const float* cpb_b1 = (const float*)d_in[6];
  const float* cpb_w2 = (const float*)d_in[7];
  const float* proj_w = (const float*)d_in[8];
  const float* proj_b = (const float*)d_in[9];
  const float* tab    = (const float*)d_in[10];
  const int*   idx    = (const int*)d_in[11];
  float* out = (float*)d_out;

  float* qb   = (float*)d_ws;
  float* kb   = qb + 7077888;
  float* vbT  = kb + 7077888;
  float* aout = vbT + 7077888;
  float* rpb2 = aout + 7077888;
  float* bt   = rpb2 + 393216;

  cpb_kernel<<<961, 64, 0, stream>>>(tab, cpb_w1, cpb_b1, cpb_w2, bt);
  rpb_kernel<<<1536, 256, 0, stream>>>(bt, idx, rpb2);
  qkv_kernel<<<dim3(576, 9), 256, 0, stream>>>(x, qkv_w, q_bias, v_bias, ls,
                                               qb, kb, vbT);
  attn_kernel<<<864, 256, 0, stream>>>(qb, kb, vbT, rpb2, ls, aout);
  proj_kernel<<<dim3(576, 3), 256, 0, stream>>>(aout, proj_w, proj_b, out);
}

// Round 4
// 114.048 us; speedup vs baseline: 3.1706x; 2.0270x over previous
//
#include <hip/hip_runtime.h>

#define CC 192
#define LOG100 4.6051701859880914f
#define PSHIFT 11.0f   // softmax-invariant scale: keeps fp16 P out of subnormals

typedef _Float16 half8v __attribute__((ext_vector_type(8)));
typedef _Float16 half4v __attribute__((ext_vector_type(4)));
typedef float f32x4 __attribute__((ext_vector_type(4)));

static __device__ __forceinline__ f32x4 mfma_k32(half8v a, half8v b, f32x4 c) {
#if __has_builtin(__builtin_amdgcn_mfma_f32_16x16x32_f16)
  return __builtin_amdgcn_mfma_f32_16x16x32_f16(a, b, c, 0, 0, 0);
#else
  asm("v_mfma_f32_16x16x32_f16 %0, %1, %2, %0" : "+v"(c) : "v"(a), "v"(b));
  return c;
#endif
}
static __device__ __forceinline__ f32x4 mfma_k16(half4v a, half4v b, f32x4 c) {
#if __has_builtin(__builtin_amdgcn_mfma_f32_16x16x16f16)
  return __builtin_amdgcn_mfma_f32_16x16x16f16(a, b, c, 0, 0, 0);
#else
  asm("v_mfma_f32_16x16x16_f16 %0, %1, %2, %0" : "+v"(c) : "v"(a), "v"(b));
  return c;
#endif
}

// ---------------------------------------------------------------------------
// cvt_x: fused roll(-8)+window gather, f32 -> fp16, xh[token][c]
// ---------------------------------------------------------------------------
__global__ __launch_bounds__(256) void cvt_x(const float* __restrict__ x,
                                             _Float16* __restrict__ xh)
{
  const int q = blockIdx.x * 256 + threadIdx.x;   // float4 units: 36864*48
  const int token = q / 48;
  const int c4 = q - token * 48;
  const int wb = token >> 8;
  const int n = token & 255;
  const int b = wb / 36;
  const int wq = wb - b * 36;
  const int wy = wq / 6;
  const int wx = wq - wy * 6;
  const int iy = (wy * 16 + (n >> 4) + 8) % 96;
  const int ix = (wx * 16 + (n & 15) + 8) % 96;
  const float4 v = *(const float4*)(x + (size_t)((b * 96 + iy) * 96 + ix) * CC + c4 * 4);
  half4v hv = {(_Float16)v.x, (_Float16)v.y, (_Float16)v.z, (_Float16)v.w};
  *(half4v*)(xh + (size_t)token * CC + c4 * 4) = hv;
}

// ---------------------------------------------------------------------------
// cvt_w: qkv_w (576x192) and proj_w (192x192) -> fp16
// ---------------------------------------------------------------------------
__global__ __launch_bounds__(256) void cvt_w(const float* __restrict__ qkvw,
                                             const float* __restrict__ projw,
                                             _Float16* __restrict__ wh,
                                             _Float16* __restrict__ ph)
{
  const int q = blockIdx.x * 256 + threadIdx.x;   // 0..36863
  float4 v;
  _Float16* dst;
  int off;
  if (q < 27648) { v = *(const float4*)(qkvw + q * 4); dst = wh; off = q * 4; }
  else { const int p = q - 27648; v = *(const float4*)(projw + p * 4); dst = ph; off = p * 4; }
  half4v hv = {(_Float16)v.x, (_Float16)v.y, (_Float16)v.z, (_Float16)v.w};
  *(half4v*)(dst + off) = hv;
}

// ---------------------------------------------------------------------------
// CPB MLP
// ---------------------------------------------------------------------------
__global__ __launch_bounds__(64) void cpb_kernel(
    const float* __restrict__ tab, const float* __restrict__ w1,
    const float* __restrict__ b1, const float* __restrict__ w2,
    float* __restrict__ bt)
{
  const int p = blockIdx.x;
  const int lane = threadIdx.x;
  const float t0 = tab[p*2+0];
  const float t1 = tab[p*2+1];
  float a0=0.f,a1=0.f,a2=0.f,a3=0.f,a4=0.f,a5=0.f;
  for (int j = lane; j < 512; j += 64) {
    float hv = fmaxf(fmaf(t0, w1[2*j], fmaf(t1, w1[2*j+1], b1[j])), 0.f);
    a0 = fmaf(hv, w2[0*512+j], a0);
    a1 = fmaf(hv, w2[1*512+j], a1);
    a2 = fmaf(hv, w2[2*512+j], a2);
    a3 = fmaf(hv, w2[3*512+j], a3);
    a4 = fmaf(hv, w2[4*512+j], a4);
    a5 = fmaf(hv, w2[5*512+j], a5);
  }
  #pragma unroll
  for (int off = 32; off > 0; off >>= 1) {
    a0 += __shfl_down(a0, off);
    a1 += __shfl_down(a1, off);
    a2 += __shfl_down(a2, off);
    a3 += __shfl_down(a3, off);
    a4 += __shfl_down(a4, off);
    a5 += __shfl_down(a5, off);
  }
  if (lane == 0) {
    bt[p*6+0]=a0; bt[p*6+1]=a1; bt[p*6+2]=a2;
    bt[p*6+3]=a3; bt[p*6+4]=a4; bt[p*6+5]=a5;
  }
}

// ---------------------------------------------------------------------------
// rpb2[h][n][m] = 16*sigmoid(bt[idx[n][m]][h])  (f32)
// ---------------------------------------------------------------------------
__global__ __launch_bounds__(256) void rpb_kernel(
    const float* __restrict__ bt, const int* __restrict__ idx,
    float* __restrict__ rpb2)
{
  const int gidx = blockIdx.x * 256 + threadIdx.x;
  const int nm = gidx & 65535;
  const int h = gidx >> 16;
  const float v = bt[idx[nm]*6 + h];
  rpb2[gidx] = 16.f / (1.f + __expf(-v));
}

// ---------------------------------------------------------------------------
// qkv_mfma: C[feature][token] = W x X^T.  Full-K staging (K=192), fp16 MFMA.
// Block: 128 tokens x 64 features, 4 waves (2 feat-halves x 2 token-halves).
// Epilogue: bias + cosine-norm + scale, LDS transpose -> qh/kh [n][d], v [d][n].
// ---------------------------------------------------------------------------
__global__ __launch_bounds__(256) void qkv_mfma(
    const _Float16* __restrict__ xh, const _Float16* __restrict__ wh,
    const float* __restrict__ q_bias, const float* __restrict__ v_bias,
    const float* __restrict__ ls,
    _Float16* __restrict__ qh, _Float16* __restrict__ kh,
    _Float16* __restrict__ vhT)
{
  __shared__ _Float16 xs[128*200];
  __shared__ _Float16 wsm[64*200];
  const int tid = threadIdx.x;
  const int tok0 = blockIdx.x * 128;
  const int feat0 = blockIdx.y * 64;

  {
    const _Float16* src = xh + (size_t)tok0 * CC;
    #pragma unroll
    for (int it = 0; it < 12; it++) {
      const int u = it*256 + tid;           // 16B units, 3072 total
      const int row = u / 24, uu = u - row*24;
      *(float4*)(xs + row*200 + uu*8) = *(const float4*)(src + u*8);
    }
    const _Float16* wsrc = wh + (size_t)feat0 * CC;
    #pragma unroll
    for (int it = 0; it < 6; it++) {
      const int u = it*256 + tid;           // 1536 total
      const int row = u / 24, uu = u - row*24;
      *(float4*)(wsm + row*200 + uu*8) = *(const float4*)(wsrc + u*8);
    }
  }
  __syncthreads();

  const int lane = tid & 63;
  const int wv = tid >> 6;
  const int g = lane >> 4;
  const int r = lane & 15;
  const int wf = (wv & 1) * 32;
  const int wt = (wv >> 1) * 64;

  f32x4 acc[2][4];
  #pragma unroll
  for (int f = 0; f < 2; f++)
    #pragma unroll
    for (int t = 0; t < 4; t++) acc[f][t] = (f32x4){0.f,0.f,0.f,0.f};

  const _Float16* wbase = wsm + (wf + r)*200 + g*8;
  const _Float16* xbase = xs + (wt + r)*200 + g*8;
  #pragma unroll
  for (int ks = 0; ks < 6; ks++) {
    half8v af[2], bf[4];
    #pragma unroll
    for (int f = 0; f < 2; f++) af[f] = *(const half8v*)(wbase + f*16*200 + ks*32);
    #pragma unroll
    for (int t = 0; t < 4; t++) bf[t] = *(const half8v*)(xbase + t*16*200 + ks*32);
    #pragma unroll
    for (int f = 0; f < 2; f++)
      #pragma unroll
      for (int t = 0; t < 4; t++)
        acc[f][t] = mfma_k32(af[f], bf[t], acc[f][t]);
  }
  __syncthreads();    // tiles consumed; reuse xs as scratch

  const int part = blockIdx.y / 3;                       // 0=q 1=k 2=v
  const int hloc = (blockIdx.y % 3) * 2 + (wf >> 5);     // head 0..5
  const int wbw  = tok0 >> 8;
  const int nbase = (tok0 & 255) + wt;
  const size_t slice = ((size_t)wbw * 6 + hloc) * 8192;
  _Float16* scr = xs + wv * 2880;

  if (part < 2) {
    float4 qb4[2];
    float scale = 1.f;
    if (part == 0) {
      #pragma unroll
      for (int f = 0; f < 2; f++)
        qb4[f] = *(const float4*)(q_bias + hloc*32 + f*16 + g*4);
      scale = __expf(fminf(ls[hloc], LOG100));
    } else {
      qb4[0] = make_float4(0.f,0.f,0.f,0.f);
      qb4[1] = make_float4(0.f,0.f,0.f,0.f);
    }
    #pragma unroll
    for (int t = 0; t < 4; t++) {
      float v0[2][4];
      float ss = 0.f;
      #pragma unroll
      for (int f = 0; f < 2; f++) {
        const float* qbp = (const float*)&qb4[f];
        #pragma unroll
        for (int j2 = 0; j2 < 4; j2++) {
          const float val = acc[f][t][j2] + qbp[j2];
          v0[f][j2] = val;
          ss = fmaf(val, val, ss);
        }
      }
      ss += __shfl_xor(ss, 16);
      ss += __shfl_xor(ss, 32);
      const float rn = scale / (sqrtf(ss) + 1e-12f);
      #pragma unroll
      for (int f = 0; f < 2; f++) {
        half4v hv;
        #pragma unroll
        for (int j2 = 0; j2 < 4; j2++) hv[j2] = (_Float16)(v0[f][j2] * rn);
        *(half4v*)(scr + (t*16 + r)*40 + f*16 + g*4) = hv;
      }
    }
    _Float16* dst = (part == 0 ? qh : kh) + slice;
    #pragma unroll
    for (int it2 = 0; it2 < 2; it2++) {
      const int tl = it2*32 + (lane >> 1);
      const int sel = (lane & 1) * 16;
      #pragma unroll
      for (int i8 = 0; i8 < 2; i8++) {
        const float4 vv = *(float4*)(scr + tl*40 + sel + i8*8);
        *(float4*)(dst + (size_t)(nbase + tl)*32 + sel + i8*8) = vv;
      }
    }
  } else {
    float4 vb4[2];
    #pragma unroll
    for (int f = 0; f < 2; f++)
      vb4[f] = *(const float4*)(v_bias + hloc*32 + f*16 + g*4);
    #pragma unroll
    for (int t = 0; t < 4; t++) {
      #pragma unroll
      for (int f = 0; f < 2; f++) {
        const float* vbp = (const float*)&vb4[f];
        #pragma unroll
        for (int j2 = 0; j2 < 4; j2++)
          scr[(f*16 + g*4 + j2)*72 + t*16 + r] = (_Float16)(acc[f][t][j2] + vbp[j2]);
      }
    }
    _Float16* dst = vhT + slice;
    const int drow = lane >> 1;
    const int sel = (lane & 1) * 32;
    #pragma unroll
    for (int i8 = 0; i8 < 4; i8++) {
      const float4 vv = *(float4*)(scr + drow*72 + sel + i8*8);
      *(float4*)(dst + (size_t)drow*256 + nbase + sel + i8*8) = vv;
    }
  }
}

// ---------------------------------------------------------------------------
// MFMA attention, fp16 I/O. S^T = mfma(K,Q); zero-shuffle P -> PV.
// P scaled by exp(PSHIFT) to stay in fp16 normal range (softmax-invariant).
// ---------------------------------------------------------------------------
__global__ __launch_bounds__(256) void attn_kernel(
    const _Float16* __restrict__ qh, const _Float16* __restrict__ kh,
    const _Float16* __restrict__ vhT, const float* __restrict__ rpb2,
    const float* __restrict__ ls, _Float16* __restrict__ ah)
{
  __shared__ half8v kf[16][64];
  __shared__ half4v vf[16][2][64];
  const int tid = threadIdx.x;
  const int bx = blockIdx.x;          // wb*6 + h
  const int wb = bx / 6;
  const int h  = bx - wb*6;
  const size_t slice = (size_t)bx * 8192;

  {
    const int j = tid >> 4, rr = tid & 15;
    const _Float16* src = kh + slice + (size_t)tid * 32;
    #pragma unroll
    for (int g4 = 0; g4 < 4; g4++)
      kf[j][16*g4 + rr] = *(const half8v*)(src + g4*8);
  }
  {
    const int mc = tid >> 4, rr = tid & 15;
    #pragma unroll
    for (int dt = 0; dt < 2; dt++) {
      const _Float16* src = vhT + slice + (size_t)(dt*16 + rr)*256 + mc*16;
      #pragma unroll
      for (int g4 = 0; g4 < 4; g4++)
        vf[mc][dt][16*g4 + rr] = *(const half4v*)(src + g4*4);
    }
  }
  const float bound = __expf(fminf(ls[h], LOG100)) + 16.0f;
  __syncthreads();

  const int lane = tid & 63;
  const int wv   = tid >> 6;
  const int g    = lane >> 4;
  const int c    = lane & 15;

  const int wq = wb % 36;
  const int wy = wq / 6;
  const int wx = wq - wy*6;
  const bool lastY = (wy == 5);
  const float xmask = ((wx == 5) && ((g >= 2) != (c >= 8))) ? -100.f : 0.f;

  #pragma unroll
  for (int ii = 0; ii < 4; ii++) {
    const int i = wv*4 + ii;
    const bool iHi = (i >= 8);
    const half8v bq = *(const half8v*)(qh + slice + (size_t)(i*16 + c)*32 + 8*g);
    const float* rp = rpb2 + h*65536 + (i*16 + c)*256 + 4*g;
    f32x4 o0 = {0.f,0.f,0.f,0.f};
    f32x4 o1 = {0.f,0.f,0.f,0.f};
    float dsum = 0.f;
    #pragma unroll
    for (int j = 0; j < 16; j++) {
      f32x4 zero = {0.f,0.f,0.f,0.f};
      f32x4 s = mfma_k32(kf[j][lane], bq, zero);
      const float4 b4 = *(const float4*)(rp + j*16);
      const float madd = (lastY && ((j >= 8) != iHi)) ? -100.f : xmask;
      const float adj = madd - bound + PSHIFT;
      const float p0 = __expf(s[0] + b4.x + adj);
      const float p1 = __expf(s[1] + b4.y + adj);
      const float p2 = __expf(s[2] + b4.z + adj);
      const float p3 = __expf(s[3] + b4.w + adj);
      dsum += (p0 + p1) + (p2 + p3);
      half4v pf;
      pf[0]=(_Float16)p0; pf[1]=(_Float16)p1; pf[2]=(_Float16)p2; pf[3]=(_Float16)p3;
      o0 = mfma_k16(vf[j][0][lane], pf, o0);
      o1 = mfma_k16(vf[j][1][lane], pf, o1);
    }
    float d = dsum + __shfl_xor(dsum, 16);
    d += __shfl_xor(d, 32);
    const float inv = 1.f / d;
    _Float16* obase = ah + (size_t)(wb*256 + i*16 + c)*CC + h*32 + 4*g;
    half4v h0, h1;
    #pragma unroll
    for (int j2 = 0; j2 < 4; j2++) {
      h0[j2] = (_Float16)(o0[j2] * inv);
      h1[j2] = (_Float16)(o1[j2] * inv);
    }
    *(half4v*)obase = h0;
    *(half4v*)(obase + 16) = h1;
  }
}

// ---------------------------------------------------------------------------
// proj_mfma: C[out-feature][token] = Pw x A^T, fp16 MFMA, f32 scatter out.
// ---------------------------------------------------------------------------
__global__ __launch_bounds__(256) void proj_mfma(
    const _Float16* __restrict__ ah, const _Float16* __restrict__ ph,
    const float* __restrict__ pb, float* __restrict__ out)
{
  __shared__ _Float16 xs[128*200];
  __shared__ _Float16 wsm[64*200];
  const int tid = threadIdx.x;
  const int tok0 = blockIdx.x * 128;
  const int feat0 = blockIdx.y * 64;

  {
    const _Float16* src = ah + (size_t)tok0 * CC;
    #pragma unroll
    for (int it = 0; it < 12; it++) {
      const int u = it*256 + tid;
      const int row = u / 24, uu = u - row*24;
      *(float4*)(xs + row*200 + uu*8) = *(const float4*)(src + u*8);
    }
    const _Float16* wsrc = ph + (size_t)feat0 * CC;
    #pragma unroll
    for (int it = 0; it < 6; it++) {
      const int u = it*256 + tid;
      const int row = u / 24, uu = u - row*24;
      *(float4*)(wsm + row*200 + uu*8) = *(const float4*)(wsrc + u*8);
    }
  }
  __syncthreads();

  const int lane = tid & 63;
  const int wv = tid >> 6;
  const int g = lane >> 4;
  const int r = lane & 15;
  const int wf = (wv & 1) * 32;
  const int wt = (wv >> 1) * 64;

  f32x4 acc[2][4];
  #pragma unroll
  for (int f = 0; f < 2; f++)
    #pragma unroll
    for (int t = 0; t < 4; t++) acc[f][t] = (f32x4){0.f,0.f,0.f,0.f};

  const _Float16* wbase = wsm + (wf + r)*200 + g*8;
  const _Float16* xbase = xs + (wt + r)*200 + g*8;
  #pragma unroll
  for (int ks = 0; ks < 6; ks++) {
    half8v af[2], bf[4];
    #pragma unroll
    for (int f = 0; f < 2; f++) af[f] = *(const half8v*)(wbase + f*16*200 + ks*32);
    #pragma unroll
    for (int t = 0; t < 4; t++) bf[t] = *(const half8v*)(xbase + t*16*200 + ks*32);
    #pragma unroll
    for (int f = 0; f < 2; f++)
      #pragma unroll
      for (int t = 0; t < 4; t++)
        acc[f][t] = mfma_k32(af[f], bf[t], acc[f][t]);
  }

  const int nf0 = feat0 + wf + g*4;
  float4 pb4[2];
  pb4[0] = *(const float4*)(pb + nf0);
  pb4[1] = *(const float4*)(pb + nf0 + 16);
  #pragma unroll
  for (int t = 0; t < 4; t++) {
    const int tg = tok0 + wt + t*16 + r;
    const int wb2 = tg >> 8;
    const int n2 = tg & 255;
    const int b = wb2 / 36;
    const int wq = wb2 - b*36;
    const int wy = wq / 6;
    const int wx = wq - wy*6;
    const int iy = (wy*16 + (n2 >> 4) + 8) % 96;
    const int ix = (wx*16 + (n2 & 15) + 8) % 96;
    float* obase = out + (size_t)((b*96 + iy)*96 + ix)*CC + nf0;
    #pragma unroll
    for (int f = 0; f < 2; f++) {
      const float* pbp = (const float*)&pb4[f];
      *(float4*)(obase + f*16) = make_float4(
          acc[f][t][0] + pbp[0], acc[f][t][1] + pbp[1],
          acc[f][t][2] + pbp[2], acc[f][t][3] + pbp[3]);
    }
  }
}

extern "C" void kernel_launch(void* const* d_in, const int* in_sizes, int n_in,
                              void* d_out, int out_size, void* d_ws, size_t ws_size,
                              hipStream_t stream) {
  const float* x      = (const float*)d_in[0];
  const float* qkv_w  = (const float*)d_in[1];
  const float* q_bias = (const float*)d_in[2];
  const float* v_bias = (const float*)d_in[3];
  const float* ls     = (const float*)d_in[4];
  const float* cpb_w1 = (const float*)d_in[5];
  const float* cpb_b1 = (const float*)d_in[6];
  const float* cpb_w2 = (const float*)d_in[7];
  const float* proj_w = (const float*)d_in[8];
  const float* proj_b = (const float*)d_in[9];
  const float* tab    = (const float*)d_in[10];
  const int*   idx    = (const int*)d_in[11];
  float* out = (float*)d_out;

  char* wsb = (char*)d_ws;
  _Float16* xh  = (_Float16*)(wsb);
  _Float16* qh  = (_Float16*)(wsb + 1*14155776);
  _Float16* kh  = (_Float16*)(wsb + 2*14155776);
  _Float16* vhT = (_Float16*)(wsb + 3*14155776);
  _Float16* ah  = (_Float16*)(wsb + 4*14155776);
  _Float16* wh  = (_Float16*)(wsb + 5*14155776);
  _Float16* ph  = (_Float16*)(wsb + 5*14155776 + 221184);
  float* rpb2   = (float*)(wsb + 5*14155776 + 221184 + 73728);
  float* bt     = (float*)(wsb + 5*14155776 + 221184 + 73728 + 1572864);

  cvt_x<<<6912, 256, 0, stream>>>(x, xh);
  cvt_w<<<144, 256, 0, stream>>>(qkv_w, proj_w, wh, ph);
  cpb_kernel<<<961, 64, 0, stream>>>(tab, cpb_w1, cpb_b1, cpb_w2, bt);
  rpb_kernel<<<1536, 256, 0, stream>>>(bt, idx, rpb2);
  qkv_mfma<<<dim3(288, 9), 256, 0, stream>>>(xh, wh, q_bias, v_bias, ls,
                                             qh, kh, vhT);
  attn_kernel<<<864, 256, 0, stream>>>(qh, kh, vhT, rpb2, ls, ah);
  proj_mfma<<<dim3(288, 3), 256, 0, stream>>>(ah, ph, proj_b, out);
}